// Round 15
// baseline (121.818 us; speedup 1.0000x reference)
//
#include <hip/hip_runtime.h>

// Problem constants (fixed by reference)
#define BATCH   16384
#define NFEAT   512
#define NTREE   64
#define NDEPTH  6
#define NLEAF   64
#define NDOUT   64
#define NLOGIT  384   // NDEPTH * NTREE

typedef float    f32x4  __attribute__((ext_vector_type(4)));
typedef short    short8 __attribute__((ext_vector_type(8)));
typedef _Float16 half8  __attribute__((ext_vector_type(8)));
typedef _Float16 h2     __attribute__((ext_vector_type(2)));

union U8 { unsigned short u[8]; short8 v; half8 h; };
union HP { _Float16 h[4]; ushort4 u; };
union HS { _Float16 h; unsigned short s; };
union H8 { h2 p[4]; half8 v; };

// fast fp32 -> bf16, round-half-up (+0x8000): 2 VALU ops
__device__ __forceinline__ unsigned short f2bf(float f) {
    union { float f; unsigned int u; } c; c.f = f;
    return (unsigned short)((c.u + 0x8000u) >> 16);
}

__device__ __forceinline__ unsigned short f2h(float f) {
    HS s; s.h = (_Float16)f; return s.s;
}

// ---------------------------------------------------------------------------
// prep — FRAGMENT-ORDERED operand layouts (R11-verified): every fused fragment
// load is a 64-lane x 16B CONTIGUOUS read.
//  blocks 0..63  -> V3: per (t, nt, ks): lane λ=quad*16+l15, elems j:
//        V3[(((t*8)+nt*2+ks)*64+λ)*8+j] = fp16(leaf[t][ks*32+quad*8+j][nt*16+l15]/64)
//  blocks 64..159-> Wt3: per (kb, g, ks): lane λ=qk*16+(n&15):
//        Wt3[(((kb*24+g)*2+ks)*64+λ)*8+j] = bf16(W[d][kb*64+ks*32+qk*8+j][t]),
//        n = d*64+t, g = n>>4
// ---------------------------------------------------------------------------
__global__ __launch_bounds__(256) void prep(const float* __restrict__ leaf,
                                            const float* __restrict__ W,
                                            unsigned short* __restrict__ V3,
                                            unsigned short* __restrict__ Wt3) {
    __shared__ float T[64 * 65];
    const int tid = threadIdx.x;
    if (blockIdx.x < 64) {
        const int t = blockIdx.x;
        const float* src = leaf + (size_t)t * 4096;
        for (int j = 0; j < 4; ++j) {
            int idx = tid + 256 * j;            // 0..1023 float4s
            int l = idx >> 4, d4 = idx & 15;
            float4 v = *(const float4*)(src + l * 64 + d4 * 4);
            T[l * 65 + d4 * 4 + 0] = v.x;
            T[l * 65 + d4 * 4 + 1] = v.y;
            T[l * 65 + d4 * 4 + 2] = v.z;
            T[l * 65 + d4 * 4 + 3] = v.w;
        }
        __syncthreads();                        // T[l*65+d] = leaf[t][l][d]
        #pragma unroll
        for (int jj = 0; jj < 2; ++jj) {
            int idx = tid + 256 * jj;           // 0..511: (d, leaf-octet o)
            int d = idx >> 3, o = idx & 7;
            int nt = d >> 4, l15 = d & 15;
            int ks = o >> 2, qd = o & 3;
            int lam = qd * 16 + l15;
            U8 u;
            #pragma unroll
            for (int j = 0; j < 8; ++j)
                u.u[j] = f2h(T[(o * 8 + j) * 65 + d] * 0.015625f);
            *(short8*)(V3 + (((size_t)t * 8 + nt * 2 + ks) * 64 + lam) * 8) = u.v;
        }
    } else {
        const int bid = blockIdx.x - 64;        // 0..95
        const int d = bid >> 4, f0 = (bid & 15) * 32;
        for (int j = 0; j < 2; ++j) {
            int idx = tid + 256 * j;            // 0..511 float4s (32 f x 64 t)
            int f = idx >> 4, c4 = idx & 15;
            float4 v = *(const float4*)(W + ((size_t)d * 512 + f0 + f) * 64 + c4 * 4);
            T[f * 65 + c4 * 4 + 0] = v.x;
            T[f * 65 + c4 * 4 + 1] = v.y;
            T[f * 65 + c4 * 4 + 2] = v.z;
            T[f * 65 + c4 * 4 + 3] = v.w;
        }
        __syncthreads();                        // T[f*65+t] = W[d][f0+f][t]
        const int t = tid >> 2, c8 = tid & 3;
        U8 u;
        #pragma unroll
        for (int i = 0; i < 8; ++i) u.u[i] = f2bf(T[(c8 * 8 + i) * 65 + t]);
        int k0 = f0 + c8 * 8;
        int kb = k0 >> 6, ks = (k0 >> 5) & 1, qk = (k0 >> 3) & 3;
        int g  = d * 4 + (t >> 4);
        int lam = qk * 16 + (t & 15);
        *(short8*)(Wt3 + (((size_t)kb * 24 + g) * 2 + ks) * 512 + lam * 8) = u.v;
    }
}

// ---------------------------------------------------------------------------
// fused: 32-row tiles, 512 threads (512 blocks, 2/CU). R12-R14 post-mortems:
// per-K-step memory latency was absorbed at BLOCK-WIDE barriers — a collective
// stall immune to TLP (R13), tile size (R14), and traffic (R14). This version
// makes phase 1 BARRIER-FREE with an EXPLICIT register ping-pong pipeline
// (R11's proven load(kb+1);compute(kb) shape, but A in named register sets —
// per-wave counted vmcnt instead of block-collective vmcnt(0) drains).
// R12's barrier-free failure was the missing explicit pipeline, not the idea.
//   phase 1 — wave w owns 48 logits (3 nt) x 32 rows (2 mt); A global->reg
//     (lane-private 2x16B contiguous), B 1KB-coalesced from Wt3; both 1-step
//     lookahead in named reg sets; no LDS, no barriers.
//   phase 2 — tree (verbatim R13, HW-passed): wave owns 8 trees, acc[2][4],
//     1-deep V3 prefetch, packed-fp16 buildA, cross-wave fp16 reduce.
// LDS: sp 24K | red 40K (separate). 64 KB, 2 blocks/CU.
// ---------------------------------------------------------------------------
__global__ __launch_bounds__(512) void fused(const float* __restrict__ x,
                                             const unsigned short* __restrict__ Wt3,
                                             const float* __restrict__ bias,
                                             const unsigned short* __restrict__ V3,
                                             float* __restrict__ out) {
    __shared__ char SM[64 * 1024];
    _Float16*       sp  = (_Float16*)SM;                   // [384][32]  24 KB
    _Float16*       red = (_Float16*)(SM + 24 * 1024);     // [8][64][40] 40 KB

    const int tid  = threadIdx.x;
    const int w = tid >> 6, lane = tid & 63;
    const int quad = lane >> 4, l15 = lane & 15;
    const int r0 = blockIdx.x * 32;
    const int w3 = w * 3;

    // ================= phase 1: logits (no barriers, reg ping-pong) ========
    f32x4 acc1[2][3];
    #pragma unroll
    for (int mt = 0; mt < 2; ++mt)
        #pragma unroll
        for (int nt = 0; nt < 3; ++nt)
            acc1[mt][nt] = (f32x4){0.f, 0.f, 0.f, 0.f};

    auto loadA = [&](int kb, float4 (*pa)[2], float4 (*pb)[2]) {
        #pragma unroll
        for (int mt = 0; mt < 2; ++mt)
            #pragma unroll
            for (int ks = 0; ks < 2; ++ks) {
                const float* g = x + (size_t)(r0 + mt * 16 + l15) * NFEAT
                               + kb * 64 + ks * 32 + quad * 8;
                pa[mt][ks] = *(const float4*)(g);
                pb[mt][ks] = *(const float4*)(g + 4);
            }
    };
    auto loadBv = [&](int kb, short8 (*bf)[2]) {
        #pragma unroll
        for (int nt = 0; nt < 3; ++nt)
            #pragma unroll
            for (int ks = 0; ks < 2; ++ks)
                bf[nt][ks] = *(const short8*)(Wt3 +
                    (((size_t)kb * 24 + w3 + nt) * 2 + ks) * 512 + lane * 8);
    };
    auto computeStep = [&](float4 (*pa)[2], float4 (*pb)[2], short8 (*bf)[2]) {
        short8 aF[2][2];
        #pragma unroll
        for (int mt = 0; mt < 2; ++mt)
            #pragma unroll
            for (int ks = 0; ks < 2; ++ks) {
                U8 u;
                u.u[0] = f2bf(pa[mt][ks].x); u.u[1] = f2bf(pa[mt][ks].y);
                u.u[2] = f2bf(pa[mt][ks].z); u.u[3] = f2bf(pa[mt][ks].w);
                u.u[4] = f2bf(pb[mt][ks].x); u.u[5] = f2bf(pb[mt][ks].y);
                u.u[6] = f2bf(pb[mt][ks].z); u.u[7] = f2bf(pb[mt][ks].w);
                aF[mt][ks] = u.v;
            }
        #pragma unroll
        for (int mt = 0; mt < 2; ++mt)
            #pragma unroll
            for (int nt = 0; nt < 3; ++nt)
                #pragma unroll
                for (int ks = 0; ks < 2; ++ks)
                    acc1[mt][nt] = __builtin_amdgcn_mfma_f32_16x16x32_bf16(
                        aF[mt][ks], bf[nt][ks], acc1[mt][nt], 0, 0, 0);
    };

    float4 rAa[2][2], rAb[2][2], rBa[2][2], rBb[2][2];
    short8 bC[3][2], bN[3][2];
    loadA(0, rAa, rAb);
    loadBv(0, bC);
    #pragma unroll
    for (int kp = 0; kp < 4; ++kp) {
        int kb = kp * 2;
        loadA(kb + 1, rBa, rBb);            // in flight over compute(kb)
        loadBv(kb + 1, bN);
        computeStep(rAa, rAb, bC);
        if (kb + 2 < 8) {
            loadA(kb + 2, rAa, rAb);        // in flight over compute(kb+1)
            loadBv(kb + 2, bC);
        }
        computeStep(rBa, rBb, bN);
    }

    // bias + sigmoid -> sp[n][b_loc] fp16
    #pragma unroll
    for (int nt = 0; nt < 3; ++nt) {
        int n = w * 48 + nt * 16 + l15;
        float bv = bias[n];
        #pragma unroll
        for (int mt = 0; mt < 2; ++mt) {
            HP h;
            #pragma unroll
            for (int r = 0; r < 4; ++r) {
                float z = acc1[mt][nt][r] + bv;
                h.h[r] = (_Float16)(1.0f / (1.0f + __expf(-z)));
            }
            *(ushort4*)(sp + n * 32 + mt * 16 + quad * 4) = h.u;
        }
    }
    __syncthreads();

    // ================= phase 2: tree (wave w owns trees 8w..8w+7) ==========
    const _Float16* V3h = (const _Float16*)V3;

    f32x4 acc[2][4];
    #pragma unroll
    for (int mt = 0; mt < 2; ++mt)
        #pragma unroll
        for (int nt = 0; nt < 4; ++nt)
            acc[mt][nt] = (f32x4){0.f, 0.f, 0.f, 0.f};

    auto loadB = [&](int t, half8 (*bf)[2]) {
        #pragma unroll
        for (int nt = 0; nt < 4; ++nt)
            #pragma unroll
            for (int ks = 0; ks < 2; ++ks)
                bf[nt][ks] = *(const half8*)(V3h +
                    (((size_t)t * 8 + nt * 2 + ks) * 64 + lane) * 8);
    };
    auto buildA = [&](int t, half8 (*af)[2]) {
        const _Float16 one = (_Float16)1.0f;
        #pragma unroll
        for (int mt = 0; mt < 2; ++mt) {
            int rl = mt * 16 + l15;
            _Float16 p0 = sp[(0 * 64 + t) * 32 + rl];
            _Float16 p1 = sp[(1 * 64 + t) * 32 + rl];
            _Float16 p2 = sp[(2 * 64 + t) * 32 + rl];
            _Float16 p3 = sp[(3 * 64 + t) * 32 + rl];
            _Float16 p4 = sp[(4 * 64 + t) * 32 + rl];
            _Float16 p5 = sp[(5 * 64 + t) * 32 + rl];
            _Float16 q1 = (quad & 2) ? (_Float16)(one - p1) : p1;
            _Float16 q2 = (quad & 1) ? (_Float16)(one - p2) : p2;
            _Float16 pre  = q1 * q2;
            _Float16 pre0 = p0 * pre;
            _Float16 pre1 = (_Float16)(one - p0) * pre;
            h2 t45 = { p4, (_Float16)(one - p4) };
            h2 t5  = { p5, (_Float16)(one - p5) };
            h2 a34 = (h2){ p3, p3 } * t45;
            _Float16 q3 = one - p3;
            h2 b34 = (h2){ q3, q3 } * t45;
            h2 w0 = (h2){ a34.x, a34.x } * t5;
            h2 w1 = (h2){ a34.y, a34.y } * t5;
            h2 w2 = (h2){ b34.x, b34.x } * t5;
            h2 w3 = (h2){ b34.y, b34.y } * t5;
            h2 P0 = { pre0, pre0 }, P1 = { pre1, pre1 };
            H8 a0, a1;
            a0.p[0] = P0 * w0; a0.p[1] = P0 * w1;
            a0.p[2] = P0 * w2; a0.p[3] = P0 * w3;
            a1.p[0] = P1 * w0; a1.p[1] = P1 * w1;
            a1.p[2] = P1 * w2; a1.p[3] = P1 * w3;
            af[mt][0] = a0.v;
            af[mt][1] = a1.v;
        }
    };

    half8 bA[4][2], bB[4][2], aF2[2][2];
    loadB(w * 8, bA);
    #pragma unroll 2
    for (int tl = 0; tl < 8; ++tl) {
        const int t = w * 8 + tl;
        half8 (*cur)[2] = (tl & 1) ? bB : bA;
        half8 (*nxt)[2] = (tl & 1) ? bA : bB;
        if (tl + 1 < 8) loadB(t + 1, nxt);    // in flight over aF build
        buildA(t, aF2);
        #pragma unroll
        for (int mt = 0; mt < 2; ++mt)
            #pragma unroll
            for (int nt = 0; nt < 4; ++nt)
                #pragma unroll
                for (int ks = 0; ks < 2; ++ks)
                    acc[mt][nt] = __builtin_amdgcn_mfma_f32_16x16x32_f16(
                        aF2[mt][ks], cur[nt][ks], acc[mt][nt], 0, 0, 0);
    }

    // cross-wave reduce: write fp16 partials [w][d][b]
    #pragma unroll
    for (int mt = 0; mt < 2; ++mt)
        #pragma unroll
        for (int nt = 0; nt < 4; ++nt) {
            HP h;
            #pragma unroll
            for (int r = 0; r < 4; ++r) h.h[r] = (_Float16)acc[mt][nt][r];
            *(ushort4*)(red + (w * 64 + nt * 16 + l15) * 40 + mt * 16 + quad * 4) = h.u;
        }
    __syncthreads();
    {
        int b = tid >> 4;                     // 0..31
        int doff = (tid & 15) * 4;            // 0..60
        float s[4];
        #pragma unroll
        for (int i = 0; i < 4; ++i) s[i] = 0.f;
        #pragma unroll
        for (int ww = 0; ww < 8; ++ww)
            #pragma unroll
            for (int i = 0; i < 4; ++i)
                s[i] += (float)red[(ww * 64 + doff + i) * 40 + b];
        float4 o0 = { s[0], s[1], s[2], s[3] };
        *(float4*)(out + (size_t)(r0 + b) * NDOUT + doff) = o0;
    }
}

// ---------------------------------------------------------------------------
extern "C" void kernel_launch(void* const* d_in, const int* in_sizes, int n_in,
                              void* d_out, int out_size, void* d_ws, size_t ws_size,
                              hipStream_t stream) {
    const float* x    = (const float*)d_in[0];  // (16384, 512)
    const float* W    = (const float*)d_in[1];  // (6, 512, 64)
    const float* bias = (const float*)d_in[2];  // (6, 64) flat = 384
    const float* leaf = (const float*)d_in[3];  // (64, 64, 64)
    float* out = (float*)d_out;                 // (16384, 64)

    // ws: V3 fp16 fragment-ordered (512 KB) | Wt3 bf16 fragment-ordered (384 KB)
    unsigned short* V3  = (unsigned short*)d_ws;
    unsigned short* Wt3 = V3 + (size_t)NTREE * NLEAF * NDOUT;

    prep<<<160, 256, 0, stream>>>(leaf, W, V3, Wt3);
    fused<<<BATCH / 32, 512, 0, stream>>>(x, Wt3, bias, (const unsigned short*)V3, out);
}

// Round 16
// 102.325 us; speedup vs baseline: 1.1905x; 1.1905x over previous
//
#include <hip/hip_runtime.h>

// Problem constants (fixed by reference)
#define BATCH   16384
#define NFEAT   512
#define NTREE   64
#define NDEPTH  6
#define NLEAF   64
#define NDOUT   64
#define NLOGIT  384   // NDEPTH * NTREE

typedef float    f32x4  __attribute__((ext_vector_type(4)));
typedef short    short8 __attribute__((ext_vector_type(8)));
typedef _Float16 half8  __attribute__((ext_vector_type(8)));
typedef _Float16 h2     __attribute__((ext_vector_type(2)));

union U8 { unsigned short u[8]; short8 v; half8 h; };
union HP { _Float16 h[4]; ushort4 u; };
union HS { _Float16 h; unsigned short s; };
union H8 { h2 p[4]; half8 v; };
union W4 { uint2 u; _Float16 h[4]; };
union W2 { unsigned u; _Float16 h[2]; };

// fast fp32 -> bf16, round-half-up (+0x8000): 2 VALU ops
__device__ __forceinline__ unsigned short f2bf(float f) {
    union { float f; unsigned int u; } c; c.f = f;
    return (unsigned short)((c.u + 0x8000u) >> 16);
}

__device__ __forceinline__ unsigned short f2h(float f) {
    HS s; s.h = (_Float16)f; return s.s;
}

// async global->LDS DMA, 16B per lane; lds dest must be wave-uniform base,
// HW writes lane i at base + i*16 (m97 pattern).
__device__ __forceinline__ void dma16(const void* g, void* l) {
    __builtin_amdgcn_global_load_lds(
        (const __attribute__((address_space(1))) unsigned int*)g,
        (__attribute__((address_space(3))) unsigned int*)l, 16, 0, 0);
}

// ---------------------------------------------------------------------------
// prep — FRAGMENT-ORDERED operand layouts (R11-verified): every fused fragment
// load is a 64-lane x 16B CONTIGUOUS read.
//  blocks 0..63  -> V3: per (t, nt, ks): lane λ=quad*16+l15, elems j:
//        V3[(((t*8)+nt*2+ks)*64+λ)*8+j] = fp16(leaf[t][ks*32+quad*8+j][nt*16+l15]/64)
//  blocks 64..159-> Wt3: per (kb, g, ks): lane λ=qk*16+(n&15):
//        Wt3[(((kb*24+g)*2+ks)*64+λ)*8+j] = bf16(W[d][kb*64+ks*32+qk*8+j][t]),
//        n = d*64+t, g = n>>4
// ---------------------------------------------------------------------------
__global__ __launch_bounds__(256) void prep(const float* __restrict__ leaf,
                                            const float* __restrict__ W,
                                            unsigned short* __restrict__ V3,
                                            unsigned short* __restrict__ Wt3) {
    __shared__ float T[64 * 65];
    const int tid = threadIdx.x;
    if (blockIdx.x < 64) {
        const int t = blockIdx.x;
        const float* src = leaf + (size_t)t * 4096;
        for (int j = 0; j < 4; ++j) {
            int idx = tid + 256 * j;            // 0..1023 float4s
            int l = idx >> 4, d4 = idx & 15;
            float4 v = *(const float4*)(src + l * 64 + d4 * 4);
            T[l * 65 + d4 * 4 + 0] = v.x;
            T[l * 65 + d4 * 4 + 1] = v.y;
            T[l * 65 + d4 * 4 + 2] = v.z;
            T[l * 65 + d4 * 4 + 3] = v.w;
        }
        __syncthreads();                        // T[l*65+d] = leaf[t][l][d]
        #pragma unroll
        for (int jj = 0; jj < 2; ++jj) {
            int idx = tid + 256 * jj;           // 0..511: (d, leaf-octet o)
            int d = idx >> 3, o = idx & 7;
            int nt = d >> 4, l15 = d & 15;
            int ks = o >> 2, qd = o & 3;
            int lam = qd * 16 + l15;
            U8 u;
            #pragma unroll
            for (int j = 0; j < 8; ++j)
                u.u[j] = f2h(T[(o * 8 + j) * 65 + d] * 0.015625f);
            *(short8*)(V3 + (((size_t)t * 8 + nt * 2 + ks) * 64 + lam) * 8) = u.v;
        }
    } else {
        const int bid = blockIdx.x - 64;        // 0..95
        const int d = bid >> 4, f0 = (bid & 15) * 32;
        for (int j = 0; j < 2; ++j) {
            int idx = tid + 256 * j;            // 0..511 float4s (32 f x 64 t)
            int f = idx >> 4, c4 = idx & 15;
            float4 v = *(const float4*)(W + ((size_t)d * 512 + f0 + f) * 64 + c4 * 4);
            T[f * 65 + c4 * 4 + 0] = v.x;
            T[f * 65 + c4 * 4 + 1] = v.y;
            T[f * 65 + c4 * 4 + 2] = v.z;
            T[f * 65 + c4 * 4 + 3] = v.w;
        }
        __syncthreads();                        // T[f*65+t] = W[d][f0+f][t]
        const int t = tid >> 2, c8 = tid & 3;
        U8 u;
        #pragma unroll
        for (int i = 0; i < 8; ++i) u.u[i] = f2bf(T[(c8 * 8 + i) * 65 + t]);
        int k0 = f0 + c8 * 8;
        int kb = k0 >> 6, ks = (k0 >> 5) & 1, qk = (k0 >> 3) & 3;
        int g  = d * 4 + (t >> 4);
        int lam = qk * 16 + (t & 15);
        *(short8*)(Wt3 + (((size_t)kb * 24 + g) * 2 + ks) * 512 + lam * 8) = u.v;
    }
}

// ---------------------------------------------------------------------------
// fused: EXACT R11 structure (measured best: total 100.2 µs) + ONE change:
// sp re-layout to staggered [t][rl][8] (addr_h = t*260 + rl*8 + d).
//   Old buildA: 12 scalar ds_read_u16/tree/lane at lane-stride 64B = bank
//   stride 16 -> 8-way conflict (the 2.2M SQ_LDS_BANK_CONFLICT). New: 2
//   vector reads (b64+b32) per mt at bank-stride 4 (2-way = free, quad
//   broadcasts). Epilogue writes become 4 scalar stores per (nt,mt), 2-way.
//   Sync structure, math, and all other phases identical to R11.
// LDS: sp2 33280B | As dbuf 2x8K @33280 (phase 1) / red 20K @33280 (phase 2
//      alias — phase 2 reads only sp2 + global V3). Total 53760 B.
// ---------------------------------------------------------------------------
__global__ __launch_bounds__(256) void fused(const float* __restrict__ x,
                                             const unsigned short* __restrict__ Wt3,
                                             const float* __restrict__ bias,
                                             const unsigned short* __restrict__ V3,
                                             float* __restrict__ out) {
    __shared__ char SM[54 * 1024];
    _Float16*       sp2 = (_Float16*)SM;                   // staggered, 33280 B
    float*          As0 = (float*)(SM + 33280);            // [32][64] 8 KB
    float*          As1 = (float*)(SM + 33280 + 8192);     // [32][64] 8 KB
    _Float16*       red = (_Float16*)(SM + 33280);         // [4][64][40] 20 KB alias

    const int tid  = threadIdx.x;
    const int w = tid >> 6, lane = tid & 63;
    const int quad = lane >> 4, l15 = lane & 15;
    const int r0 = blockIdx.x * 32;
    const int w6 = w * 6;

    // ================= phase 1: logits =================
    f32x4 acc1[2][6];
    #pragma unroll
    for (int mt = 0; mt < 2; ++mt)
        #pragma unroll
        for (int nt = 0; nt < 6; ++nt)
            acc1[mt][nt] = (f32x4){0.f, 0.f, 0.f, 0.f};

    auto stageA = [&](float* buf, int kb) {
        #pragma unroll
        for (int i = 0; i < 2; ++i) {
            int j  = w * 2 + i;
            int rl = j * 4 + (lane >> 4);
            const float* g = x + (size_t)(r0 + rl) * NFEAT + kb * 64
                           + (((lane & 15) ^ ((rl & 7) * 2)) * 4);
            dma16(g, (char*)buf + (size_t)j * 1024);
        }
    };
    auto loadBF = [&](int kb, short8 (*bf)[2]) {
        #pragma unroll
        for (int nt = 0; nt < 6; ++nt)
            #pragma unroll
            for (int ks = 0; ks < 2; ++ks)
                bf[nt][ks] = *(const short8*)(Wt3 +
                    (((size_t)kb * 24 + w6 + nt) * 2 + ks) * 512 + lane * 8);
    };
    auto computeStep = [&](const float* buf, short8 (*bf)[2]) {
        short8 aF[2][2];
        #pragma unroll
        for (int mt = 0; mt < 2; ++mt) {
            int r = mt * 16 + l15;
            #pragma unroll
            for (int ks = 0; ks < 2; ++ks) {
                int cb = (ks * 8 + quad * 2) ^ ((r & 7) * 2);
                float4 f0 = *(const float4*)(buf + r * 64 + cb * 4);
                float4 f1 = *(const float4*)(buf + r * 64 + cb * 4 + 4);
                U8 u;
                u.u[0] = f2bf(f0.x); u.u[1] = f2bf(f0.y);
                u.u[2] = f2bf(f0.z); u.u[3] = f2bf(f0.w);
                u.u[4] = f2bf(f1.x); u.u[5] = f2bf(f1.y);
                u.u[6] = f2bf(f1.z); u.u[7] = f2bf(f1.w);
                aF[mt][ks] = u.v;
            }
        }
        #pragma unroll
        for (int mt = 0; mt < 2; ++mt)
            #pragma unroll
            for (int nt = 0; nt < 6; ++nt)
                #pragma unroll
                for (int ks = 0; ks < 2; ++ks)
                    acc1[mt][nt] = __builtin_amdgcn_mfma_f32_16x16x32_bf16(
                        aF[mt][ks], bf[nt][ks], acc1[mt][nt], 0, 0, 0);
    };

    short8 bC[6][2], bN[6][2];
    stageA(As0, 0);
    loadBF(0, bC);
    __syncthreads();                    // tile 0 ready
    #pragma unroll
    for (int kp = 0; kp < 4; ++kp) {
        int kb = kp * 2;
        stageA(As1, kb + 1);
        loadBF(kb + 1, bN);
        computeStep(As0, bC);
        __syncthreads();                // drains kb+1 DMA after compute
        if (kb + 2 < 8) {
            stageA(As0, kb + 2);
            loadBF(kb + 2, bC);
        }
        computeStep(As1, bN);
        __syncthreads();
    }

    // bias + sigmoid -> sp2 staggered [t][rl][8] fp16  (n = d*64 + t)
    #pragma unroll
    for (int nt = 0; nt < 6; ++nt) {
        int n = w * 96 + nt * 16 + l15;
        float bv = bias[n];
        int t = n & 63, d = n >> 6;
        _Float16* base = sp2 + t * 260 + d;
        #pragma unroll
        for (int mt = 0; mt < 2; ++mt) {
            #pragma unroll
            for (int r = 0; r < 4; ++r) {
                float z = acc1[mt][nt][r] + bv;
                base[(mt * 16 + quad * 4 + r) * 8] =
                    (_Float16)(1.0f / (1.0f + __expf(-z)));
            }
        }
    }
    __syncthreads();

    // ================= phase 2: tree (wave w owns trees 16w..16w+15) =======
    const _Float16* V3h = (const _Float16*)V3;

    f32x4 acc[2][4];
    #pragma unroll
    for (int mt = 0; mt < 2; ++mt)
        #pragma unroll
        for (int nt = 0; nt < 4; ++nt)
            acc[mt][nt] = (f32x4){0.f, 0.f, 0.f, 0.f};

    auto loadB = [&](int t, half8 (*bf)[2]) {
        #pragma unroll
        for (int nt = 0; nt < 4; ++nt)
            #pragma unroll
            for (int ks = 0; ks < 2; ++ks)
                bf[nt][ks] = *(const half8*)(V3h +
                    (((size_t)t * 8 + nt * 2 + ks) * 64 + lane) * 8);
    };
    auto buildA = [&](int t, half8 (*af)[2]) {
        const _Float16 one = (_Float16)1.0f;
        #pragma unroll
        for (int mt = 0; mt < 2; ++mt) {
            int rl = mt * 16 + l15;
            const _Float16* a = sp2 + t * 260 + rl * 8;
            W4 v01; v01.u = *(const uint2*)(a);        // p0..p3 (8B-aligned)
            W2 v2;  v2.u  = *(const unsigned*)(a + 4); // p4,p5
            _Float16 p0 = v01.h[0], p1 = v01.h[1];
            _Float16 p2 = v01.h[2], p3 = v01.h[3];
            _Float16 p4 = v2.h[0],  p5 = v2.h[1];
            _Float16 q1 = (quad & 2) ? (_Float16)(one - p1) : p1;
            _Float16 q2 = (quad & 1) ? (_Float16)(one - p2) : p2;
            _Float16 pre  = q1 * q2;
            _Float16 pre0 = p0 * pre;
            _Float16 pre1 = (_Float16)(one - p0) * pre;
            h2 t45 = { p4, (_Float16)(one - p4) };
            h2 t5  = { p5, (_Float16)(one - p5) };
            h2 a34 = (h2){ p3, p3 } * t45;
            _Float16 q3 = one - p3;
            h2 b34 = (h2){ q3, q3 } * t45;
            h2 w0 = (h2){ a34.x, a34.x } * t5;
            h2 w1 = (h2){ a34.y, a34.y } * t5;
            h2 w2 = (h2){ b34.x, b34.x } * t5;
            h2 w3 = (h2){ b34.y, b34.y } * t5;
            h2 P0 = { pre0, pre0 }, P1 = { pre1, pre1 };
            H8 a0, a1;
            a0.p[0] = P0 * w0; a0.p[1] = P0 * w1;
            a0.p[2] = P0 * w2; a0.p[3] = P0 * w3;
            a1.p[0] = P1 * w0; a1.p[1] = P1 * w1;
            a1.p[2] = P1 * w2; a1.p[3] = P1 * w3;
            af[mt][0] = a0.v;
            af[mt][1] = a1.v;
        }
    };

    half8 bA[4][2], bB[4][2], aF2[2][2];
    loadB(w * 16, bA);
    #pragma unroll 2
    for (int tl = 0; tl < 16; ++tl) {
        const int t = w * 16 + tl;
        half8 (*cur)[2] = (tl & 1) ? bB : bA;
        half8 (*nxt)[2] = (tl & 1) ? bA : bB;
        if (tl + 1 < 16) loadB(t + 1, nxt);   // in flight over aF build
        buildA(t, aF2);
        #pragma unroll
        for (int mt = 0; mt < 2; ++mt)
            #pragma unroll
            for (int nt = 0; nt < 4; ++nt)
                #pragma unroll
                for (int ks = 0; ks < 2; ++ks)
                    acc[mt][nt] = __builtin_amdgcn_mfma_f32_16x16x32_f16(
                        aF2[mt][ks], cur[nt][ks], acc[mt][nt], 0, 0, 0);
    }

    // cross-wave reduce: write fp16 partials [w][d][b]  (red aliases As —
    // phase 2 reads only sp2 + global V3, so no hazard)
    #pragma unroll
    for (int mt = 0; mt < 2; ++mt)
        #pragma unroll
        for (int nt = 0; nt < 4; ++nt) {
            HP h;
            #pragma unroll
            for (int r = 0; r < 4; ++r) h.h[r] = (_Float16)acc[mt][nt][r];
            *(ushort4*)(red + (w * 64 + nt * 16 + l15) * 40 + mt * 16 + quad * 4) = h.u;
        }
    __syncthreads();
    {
        int b = tid >> 3;                     // 0..31
        int doff = (tid & 7) * 8;             // 0..56
        float s[8];
        #pragma unroll
        for (int i = 0; i < 8; ++i) s[i] = 0.f;
        #pragma unroll
        for (int ww = 0; ww < 4; ++ww)
            #pragma unroll
            for (int i = 0; i < 8; ++i)
                s[i] += (float)red[(ww * 64 + doff + i) * 40 + b];
        float4 o0 = { s[0], s[1], s[2], s[3] };
        float4 o1 = { s[4], s[5], s[6], s[7] };
        float* dst = out + (size_t)(r0 + b) * NDOUT + doff;
        *(float4*)dst = o0;
        *(float4*)(dst + 4) = o1;
    }
}

// ---------------------------------------------------------------------------
extern "C" void kernel_launch(void* const* d_in, const int* in_sizes, int n_in,
                              void* d_out, int out_size, void* d_ws, size_t ws_size,
                              hipStream_t stream) {
    const float* x    = (const float*)d_in[0];  // (16384, 512)
    const float* W    = (const float*)d_in[1];  // (6, 512, 64)
    const float* bias = (const float*)d_in[2];  // (6, 64) flat = 384
    const float* leaf = (const float*)d_in[3];  // (64, 64, 64)
    float* out = (float*)d_out;                 // (16384, 64)

    // ws: V3 fp16 fragment-ordered (512 KB) | Wt3 bf16 fragment-ordered (384 KB)
    unsigned short* V3  = (unsigned short*)d_ws;
    unsigned short* Wt3 = V3 + (size_t)NTREE * NLEAF * NDOUT;

    prep<<<160, 256, 0, stream>>>(leaf, W, V3, Wt3);
    fused<<<BATCH / 32, 256, 0, stream>>>(x, Wt3, bias, (const unsigned short*)V3, out);
}

// Round 18
// 100.188 us; speedup vs baseline: 1.2159x; 1.0213x over previous
//
#include <hip/hip_runtime.h>

// Problem constants (fixed by reference)
#define BATCH   16384
#define NFEAT   512
#define NTREE   64
#define NDEPTH  6
#define NLEAF   64
#define NDOUT   64
#define NLOGIT  384   // NDEPTH * NTREE

typedef float    f32x4  __attribute__((ext_vector_type(4)));
typedef short    short8 __attribute__((ext_vector_type(8)));
typedef _Float16 half8  __attribute__((ext_vector_type(8)));
typedef _Float16 h2     __attribute__((ext_vector_type(2)));

union U8 { unsigned short u[8]; short8 v; half8 h; };
union HP { _Float16 h[4]; ushort4 u; };
union HS { _Float16 h; unsigned short s; };
union H8 { h2 p[4]; half8 v; };

// fast fp32 -> bf16, round-half-up (+0x8000): 2 VALU ops
__device__ __forceinline__ unsigned short f2bf(float f) {
    union { float f; unsigned int u; } c; c.f = f;
    return (unsigned short)((c.u + 0x8000u) >> 16);
}

__device__ __forceinline__ unsigned short f2h(float f) {
    HS s; s.h = (_Float16)f; return s.s;
}

// async global->LDS DMA, 16B per lane; lds dest must be wave-uniform base,
// HW writes lane i at base + i*16 (m97 pattern).
__device__ __forceinline__ void dma16(const void* g, void* l) {
    __builtin_amdgcn_global_load_lds(
        (const __attribute__((address_space(1))) unsigned int*)g,
        (__attribute__((address_space(3))) unsigned int*)l, 16, 0, 0);
}

// ---------------------------------------------------------------------------
// prep — FRAGMENT-ORDERED operand layouts (R11-verified): every fused fragment
// load is a 64-lane x 16B CONTIGUOUS read.
//  blocks 0..63  -> V3: per (t, nt, ks): lane λ=quad*16+l15, elems j:
//        V3[(((t*8)+nt*2+ks)*64+λ)*8+j] = fp16(leaf[t][ks*32+quad*8+j][nt*16+l15]/64)
//  blocks 64..159-> Wt3: per (kb, g, ks): lane λ=qk*16+(n&15):
//        Wt3[(((kb*24+g)*2+ks)*64+λ)*8+j] = bf16(W[d][kb*64+ks*32+qk*8+j][t]),
//        n = d*64+t, g = n>>4
// ---------------------------------------------------------------------------
__global__ __launch_bounds__(256) void prep(const float* __restrict__ leaf,
                                            const float* __restrict__ W,
                                            unsigned short* __restrict__ V3,
                                            unsigned short* __restrict__ Wt3) {
    __shared__ float T[64 * 65];
    const int tid = threadIdx.x;
    if (blockIdx.x < 64) {
        const int t = blockIdx.x;
        const float* src = leaf + (size_t)t * 4096;
        for (int j = 0; j < 4; ++j) {
            int idx = tid + 256 * j;            // 0..1023 float4s
            int l = idx >> 4, d4 = idx & 15;
            float4 v = *(const float4*)(src + l * 64 + d4 * 4);
            T[l * 65 + d4 * 4 + 0] = v.x;
            T[l * 65 + d4 * 4 + 1] = v.y;
            T[l * 65 + d4 * 4 + 2] = v.z;
            T[l * 65 + d4 * 4 + 3] = v.w;
        }
        __syncthreads();                        // T[l*65+d] = leaf[t][l][d]
        #pragma unroll
        for (int jj = 0; jj < 2; ++jj) {
            int idx = tid + 256 * jj;           // 0..511: (d, leaf-octet o)
            int d = idx >> 3, o = idx & 7;
            int nt = d >> 4, l15 = d & 15;
            int ks = o >> 2, qd = o & 3;
            int lam = qd * 16 + l15;
            U8 u;
            #pragma unroll
            for (int j = 0; j < 8; ++j)
                u.u[j] = f2h(T[(o * 8 + j) * 65 + d] * 0.015625f);
            *(short8*)(V3 + (((size_t)t * 8 + nt * 2 + ks) * 64 + lam) * 8) = u.v;
        }
    } else {
        const int bid = blockIdx.x - 64;        // 0..95
        const int d = bid >> 4, f0 = (bid & 15) * 32;
        for (int j = 0; j < 2; ++j) {
            int idx = tid + 256 * j;            // 0..511 float4s (32 f x 64 t)
            int f = idx >> 4, c4 = idx & 15;
            float4 v = *(const float4*)(W + ((size_t)d * 512 + f0 + f) * 64 + c4 * 4);
            T[f * 65 + c4 * 4 + 0] = v.x;
            T[f * 65 + c4 * 4 + 1] = v.y;
            T[f * 65 + c4 * 4 + 2] = v.z;
            T[f * 65 + c4 * 4 + 3] = v.w;
        }
        __syncthreads();                        // T[f*65+t] = W[d][f0+f][t]
        const int t = tid >> 2, c8 = tid & 3;
        U8 u;
        #pragma unroll
        for (int i = 0; i < 8; ++i) u.u[i] = f2bf(T[(c8 * 8 + i) * 65 + t]);
        int k0 = f0 + c8 * 8;
        int kb = k0 >> 6, ks = (k0 >> 5) & 1, qk = (k0 >> 3) & 3;
        int g  = d * 4 + (t >> 4);
        int lam = qk * 16 + (t & 15);
        *(short8*)(Wt3 + (((size_t)kb * 24 + g) * 2 + ks) * 512 + lam * 8) = u.v;
    }
}

// ---------------------------------------------------------------------------
// fused: per 32 batch rows (512 blocks = 2/CU) — MEASURED-BEST structure
// (total 100.24 µs, R11):
//   phase 1 — logits, 2-phase prefetch: stage A[kb+1] (dma16, dbuf) + load
//     B[kb+1] (12 x 1KB COALESCED global from fragment-ordered Wt3, double
//     register set) BEFORE computing kb; single barrier per K-step whose
//     vmcnt(0) drain lands after ~1500cy of compute. No B LDS at all.
//   phase 2 — tree: verbatim math; loadB 1KB-coalesced from V3.
// LDS: sp 24K | As dbuf 2x8K ; red (20K) aliases As region. Total 44 KB.
// ---------------------------------------------------------------------------
__global__ __launch_bounds__(256) void fused(const float* __restrict__ x,
                                             const unsigned short* __restrict__ Wt3,
                                             const float* __restrict__ bias,
                                             const unsigned short* __restrict__ V3,
                                             float* __restrict__ out) {
    __shared__ char SM[44 * 1024];
    _Float16*       sp  = (_Float16*)SM;                   // [384][32]  24 KB
    float*          As0 = (float*)(SM + 24 * 1024);        // [32][64]    8 KB
    float*          As1 = (float*)(SM + 32 * 1024);        // [32][64]    8 KB
    _Float16*       red = (_Float16*)(SM + 24 * 1024);     // [4][64][40] 20 KB alias

    const int tid  = threadIdx.x;
    const int w = tid >> 6, lane = tid & 63;
    const int quad = lane >> 4, l15 = lane & 15;
    const int r0 = blockIdx.x * 32;
    const int w6 = w * 6;

    // ================= phase 1: logits =================
    f32x4 acc1[2][6];
    #pragma unroll
    for (int mt = 0; mt < 2; ++mt)
        #pragma unroll
        for (int nt = 0; nt < 6; ++nt)
            acc1[mt][nt] = (f32x4){0.f, 0.f, 0.f, 0.f};

    auto stageA = [&](float* buf, int kb) {
        #pragma unroll
        for (int i = 0; i < 2; ++i) {
            int j  = w * 2 + i;
            int rl = j * 4 + (lane >> 4);
            const float* g = x + (size_t)(r0 + rl) * NFEAT + kb * 64
                           + (((lane & 15) ^ ((rl & 7) * 2)) * 4);
            dma16(g, (char*)buf + (size_t)j * 1024);
        }
    };
    auto loadBF = [&](int kb, short8 (*bf)[2]) {
        #pragma unroll
        for (int nt = 0; nt < 6; ++nt)
            #pragma unroll
            for (int ks = 0; ks < 2; ++ks)
                bf[nt][ks] = *(const short8*)(Wt3 +
                    (((size_t)kb * 24 + w6 + nt) * 2 + ks) * 512 + lane * 8);
    };
    auto computeStep = [&](const float* buf, short8 (*bf)[2]) {
        short8 aF[2][2];
        #pragma unroll
        for (int mt = 0; mt < 2; ++mt) {
            int r = mt * 16 + l15;
            #pragma unroll
            for (int ks = 0; ks < 2; ++ks) {
                int cb = (ks * 8 + quad * 2) ^ ((r & 7) * 2);
                float4 f0 = *(const float4*)(buf + r * 64 + cb * 4);
                float4 f1 = *(const float4*)(buf + r * 64 + cb * 4 + 4);
                U8 u;
                u.u[0] = f2bf(f0.x); u.u[1] = f2bf(f0.y);
                u.u[2] = f2bf(f0.z); u.u[3] = f2bf(f0.w);
                u.u[4] = f2bf(f1.x); u.u[5] = f2bf(f1.y);
                u.u[6] = f2bf(f1.z); u.u[7] = f2bf(f1.w);
                aF[mt][ks] = u.v;
            }
        }
        #pragma unroll
        for (int mt = 0; mt < 2; ++mt)
            #pragma unroll
            for (int nt = 0; nt < 6; ++nt)
                #pragma unroll
                for (int ks = 0; ks < 2; ++ks)
                    acc1[mt][nt] = __builtin_amdgcn_mfma_f32_16x16x32_bf16(
                        aF[mt][ks], bf[nt][ks], acc1[mt][nt], 0, 0, 0);
    };

    short8 bC[6][2], bN[6][2];
    stageA(As0, 0);
    loadBF(0, bC);
    __syncthreads();                    // tile 0 ready
    #pragma unroll
    for (int kp = 0; kp < 4; ++kp) {
        int kb = kp * 2;
        stageA(As1, kb + 1);
        loadBF(kb + 1, bN);
        computeStep(As0, bC);
        __syncthreads();                // drains kb+1 DMA after compute
        if (kb + 2 < 8) {
            stageA(As0, kb + 2);
            loadBF(kb + 2, bC);
        }
        computeStep(As1, bN);
        __syncthreads();
    }

    // bias + sigmoid -> sp[n][b_loc] fp16
    #pragma unroll
    for (int nt = 0; nt < 6; ++nt) {
        int n = w * 96 + nt * 16 + l15;
        float bv = bias[n];
        #pragma unroll
        for (int mt = 0; mt < 2; ++mt) {
            HP h;
            #pragma unroll
            for (int r = 0; r < 4; ++r) {
                float z = acc1[mt][nt][r] + bv;
                h.h[r] = (_Float16)(1.0f / (1.0f + __expf(-z)));
            }
            *(ushort4*)(sp + n * 32 + mt * 16 + quad * 4) = h.u;
        }
    }
    __syncthreads();

    // ================= phase 2: tree =================
    const _Float16* V3h = (const _Float16*)V3;

    f32x4 acc[2][4];
    #pragma unroll
    for (int mt = 0; mt < 2; ++mt)
        #pragma unroll
        for (int nt = 0; nt < 4; ++nt)
            acc[mt][nt] = (f32x4){0.f, 0.f, 0.f, 0.f};

    auto loadB = [&](int t, half8 (*bf)[2]) {
        #pragma unroll
        for (int nt = 0; nt < 4; ++nt)
            #pragma unroll
            for (int ks = 0; ks < 2; ++ks)
                bf[nt][ks] = *(const half8*)(V3h +
                    (((size_t)t * 8 + nt * 2 + ks) * 64 + lane) * 8);
    };
    auto buildA = [&](int t, half8 (*af)[2]) {
        const _Float16 one = (_Float16)1.0f;
        #pragma unroll
        for (int mt = 0; mt < 2; ++mt) {
            int rl = mt * 16 + l15;
            _Float16 p0 = sp[(0 * 64 + t) * 32 + rl];
            _Float16 p1 = sp[(1 * 64 + t) * 32 + rl];
            _Float16 p2 = sp[(2 * 64 + t) * 32 + rl];
            _Float16 p3 = sp[(3 * 64 + t) * 32 + rl];
            _Float16 p4 = sp[(4 * 64 + t) * 32 + rl];
            _Float16 p5 = sp[(5 * 64 + t) * 32 + rl];
            _Float16 q1 = (quad & 2) ? (_Float16)(one - p1) : p1;
            _Float16 q2 = (quad & 1) ? (_Float16)(one - p2) : p2;
            _Float16 pre  = q1 * q2;
            _Float16 pre0 = p0 * pre;
            _Float16 pre1 = (_Float16)(one - p0) * pre;
            h2 t45 = { p4, (_Float16)(one - p4) };
            h2 t5  = { p5, (_Float16)(one - p5) };
            h2 a34 = (h2){ p3, p3 } * t45;
            _Float16 q3 = one - p3;
            h2 b34 = (h2){ q3, q3 } * t45;
            h2 w0 = (h2){ a34.x, a34.x } * t5;
            h2 w1 = (h2){ a34.y, a34.y } * t5;
            h2 w2 = (h2){ b34.x, b34.x } * t5;
            h2 w3 = (h2){ b34.y, b34.y } * t5;
            h2 P0 = { pre0, pre0 }, P1 = { pre1, pre1 };
            H8 a0, a1;
            a0.p[0] = P0 * w0; a0.p[1] = P0 * w1;
            a0.p[2] = P0 * w2; a0.p[3] = P0 * w3;
            a1.p[0] = P1 * w0; a1.p[1] = P1 * w1;
            a1.p[2] = P1 * w2; a1.p[3] = P1 * w3;
            af[mt][0] = a0.v;
            af[mt][1] = a1.v;
        }
    };

    half8 bA[4][2], bB[4][2], aF2[2][2];
    loadB(w * 16, bA);
    #pragma unroll 2
    for (int tl = 0; tl < 16; ++tl) {
        const int t = w * 16 + tl;
        half8 (*cur)[2] = (tl & 1) ? bB : bA;
        half8 (*nxt)[2] = (tl & 1) ? bA : bB;
        if (tl + 1 < 16) loadB(t + 1, nxt);   // in flight over aF build
        buildA(t, aF2);
        #pragma unroll
        for (int mt = 0; mt < 2; ++mt)
            #pragma unroll
            for (int nt = 0; nt < 4; ++nt)
                #pragma unroll
                for (int ks = 0; ks < 2; ++ks)
                    acc[mt][nt] = __builtin_amdgcn_mfma_f32_16x16x32_f16(
                        aF2[mt][ks], cur[nt][ks], acc[mt][nt], 0, 0, 0);
    }

    // cross-wave reduce: write fp16 partials [w][d][b]  (red aliases As —
    // phase 2 reads only sp + global V3, so no hazard)
    #pragma unroll
    for (int mt = 0; mt < 2; ++mt)
        #pragma unroll
        for (int nt = 0; nt < 4; ++nt) {
            HP h;
            #pragma unroll
            for (int r = 0; r < 4; ++r) h.h[r] = (_Float16)acc[mt][nt][r];
            *(ushort4*)(red + (w * 64 + nt * 16 + l15) * 40 + mt * 16 + quad * 4) = h.u;
        }
    __syncthreads();
    {
        int b = tid >> 3;                     // 0..31
        int doff = (tid & 7) * 8;             // 0..56
        float s[8];
        #pragma unroll
        for (int i = 0; i < 8; ++i) s[i] = 0.f;
        #pragma unroll
        for (int ww = 0; ww < 4; ++ww)
            #pragma unroll
            for (int i = 0; i < 8; ++i)
                s[i] += (float)red[(ww * 64 + doff + i) * 40 + b];
        float4 o0 = { s[0], s[1], s[2], s[3] };
        float4 o1 = { s[4], s[5], s[6], s[7] };
        float* dst = out + (size_t)(r0 + b) * NDOUT + doff;
        *(float4*)dst = o0;
        *(float4*)(dst + 4) = o1;
    }
}

// ---------------------------------------------------------------------------
extern "C" void kernel_launch(void* const* d_in, const int* in_sizes, int n_in,
                              void* d_out, int out_size, void* d_ws, size_t ws_size,
                              hipStream_t stream) {
    const float* x    = (const float*)d_in[0];  // (16384, 512)
    const float* W    = (const float*)d_in[1];  // (6, 512, 64)
    const float* bias = (const float*)d_in[2];  // (6, 64) flat = 384
    const float* leaf = (const float*)d_in[3];  // (64, 64, 64)
    float* out = (float*)d_out;                 // (16384, 64)

    // ws: V3 fp16 fragment-ordered (512 KB) | Wt3 bf16 fragment-ordered (384 KB)
    unsigned short* V3  = (unsigned short*)d_ws;
    unsigned short* Wt3 = V3 + (size_t)NTREE * NLEAF * NDOUT;

    prep<<<160, 256, 0, stream>>>(leaf, W, V3, Wt3);
    fused<<<BATCH / 32, 256, 0, stream>>>(x, Wt3, bias, (const unsigned short*)V3, out);
}